// Round 5
// baseline (95729.382 us; speedup 1.0000x reference)
//
#include <hip/hip_runtime.h>

#define VV    32000
#define EE    256
#define RSZ   1024
#define BB    64
#define TT    2048
#define NGRP  3
#define EPSLN 1e-5f

#define NBLK_PER_GRP 64
#define NBLK  (NBLK_PER_GRP * NGRP)   // 192 blocks
#define NTHR  1024                    // 16 waves = 8 k-groups x 128 threads
#define SLAB  (BB * RSZ)

#define BAR_OFF (NGRP * 2 * SLAB)     // floats offset of barrier words in d_ws

// one k-step (4 k-values): 4 rows x 2 cols FMAs against LDS weights
__device__ __forceinline__ void fma_step(const float4 (&b)[4], const float* wrow,
                                         float (&acc)[4][2]) {
#pragma unroll
    for (int j = 0; j < 4; ++j) {
        const float2 w = *reinterpret_cast<const float2*>(wrow + j * 16);
#pragma unroll
        for (int r = 0; r < 4; ++r) {
            const float a = reinterpret_cast<const float*>(&b[r])[j];
            acc[r][0] = fmaf(a, w.x, acc[r][0]);
            acc[r][1] = fmaf(a, w.y, acc[r][1]);
        }
    }
}

// NSTEPS k-steps with a depth-4 statically-indexed ring (full unroll)
template<int NSTEPS>
__device__ __forceinline__ void dot_stream(const float* const (&p)[4],
                                           const float* w,
                                           float (&acc)[4][2]) {
    float4 buf[4][4];
#pragma unroll
    for (int s = 0; s < 4; ++s)
#pragma unroll
        for (int r = 0; r < 4; ++r)
            buf[s][r] = *reinterpret_cast<const float4*>(p[r] + s * 4);

    constexpr int MAIN = NSTEPS - 4;
#pragma unroll
    for (int j = 0; j < MAIN; ++j) {          // static j -> buf[j&3] in regs
        fma_step(buf[j & 3], w + j * 64, acc);
#pragma unroll
        for (int r = 0; r < 4; ++r)
            buf[j & 3][r] = *reinterpret_cast<const float4*>(p[r] + (j + 4) * 4);
    }
#pragma unroll
    for (int j = MAIN; j < NSTEPS; ++j)       // epilogue: drain ring
        fma_step(buf[j & 3], w + j * 64, acc);
}

__global__ __launch_bounds__(NTHR, 4)
void reservoir_main(const int*   __restrict__ x,        // [B,T]
                    const float* __restrict__ embed_w,  // [V,E]
                    const float* __restrict__ Win0,
                    const float* __restrict__ Win1,
                    const float* __restrict__ Win2,
                    const float* __restrict__ Rm0,
                    const float* __restrict__ Rm1,
                    const float* __restrict__ Rm2,
                    const float* __restrict__ ln_w,
                    const float* __restrict__ ln_b,
                    float*       __restrict__ states,
                    unsigned*    __restrict__ bar,
                    float*       __restrict__ out)
{
    const int blk   = blockIdx.x;
    const int grp   = blk >> 6;              // layer
    const int gb    = blk & 63;
    const int c0    = gb << 4;               // 16-col slice
    const int tid   = threadIdx.x;
    const int kg    = tid >> 7;              // 0..7
    const int idx   = tid & 127;
    const int rbase = (idx >> 3) << 2;       // 4 rows per lane
    const int cg2   = (idx & 7) << 1;        // col pair

    const float* Wl  = (grp == 0) ? Win0 : ((grp == 1) ? Win1 : Win2);
    const float* Rl  = (grp == 0) ? Rm0  : ((grp == 1) ? Rm1  : Rm2);
    const int    Kw  = (grp == 0) ? EE : RSZ;
    const int    Kw8 = Kw >> 3;              // 32 or 128 floats per kg

    __shared__ float wlds[2048 * 16];        // 128 KB weight slab
    __shared__ float pbuf[8][32][18];        // partials

    for (int i = tid; i < RSZ * 16; i += NTHR) {
        const int k = i >> 4, c = i & 15;
        wlds[i] = Rl[(size_t)k * RSZ + c0 + c];
    }
    for (int i = tid; i < Kw * 16; i += NTHR) {
        const int k = i >> 4, c = i & 15;
        wlds[RSZ * 16 + i] = Wl[(size_t)k * RSZ + c0 + c];
    }
    __syncthreads();

    // hierarchical barrier storage: 8 leaf lines + root + epoch
    unsigned* leaf  = bar;                   // leaf i at bar[i*16]
    unsigned* root  = bar + 128;
    unsigned* epoch = bar + 160;

    float* const sl = states + (size_t)grp * 2 * SLAB;
    const float* const wRb = wlds + (kg << 7) * 16 + cg2;
    const float* const wWb = wlds + (RSZ + kg * Kw8) * 16 + cg2;

    int xidx[4];
    if (grp == 0) {
#pragma unroll
        for (int r = 0; r < 4; ++r) xidx[r] = x[(rbase + r) * TT + 0];
    }

    for (int tick = 0; tick < TT + NGRP - 1; ++tick) {
        const int t = tick - grp;            // uniform per block
        if (0 <= t && t < TT) {
            const float* sprev = sl + (size_t)((t + 1) & 1) * SLAB;

            float acc[4][2] = {{0.f,0.f},{0.f,0.f},{0.f,0.f},{0.f,0.f}};

            {   // recurrent part: s_prev @ R_l (32 k-steps)
                const float* aR[4];
#pragma unroll
                for (int r = 0; r < 4; ++r)
                    aR[r] = sprev + (size_t)(rbase + r) * RSZ + (kg << 7);
                dot_stream<32>(aR, wRb, acc);
            }
            {   // input part: cur @ W_l
                const float* aW[4];
                if (grp == 0) {
#pragma unroll
                    for (int r = 0; r < 4; ++r)
                        aW[r] = embed_w + (size_t)xidx[r] * EE + kg * Kw8;
                    dot_stream<8>(aW, wWb, acc);
                } else {
                    const float* cb = states + ((size_t)(grp - 1) * 2 + (t & 1)) * SLAB;
#pragma unroll
                    for (int r = 0; r < 4; ++r)
                        aW[r] = cb + (size_t)(rbase + r) * RSZ + kg * Kw8;
                    dot_stream<32>(aW, wWb, acc);
                }
            }

            // prefetch next tick's token indices (layer 0 only)
            if (grp == 0 && t + 1 < TT) {
#pragma unroll
                for (int r = 0; r < 4; ++r) xidx[r] = x[(rbase + r) * TT + t + 1];
            }

            // ---- flat reduce over 8 k-groups, two row-halves ----
            float* sout = sl + (size_t)(t & 1) * SLAB;

            if (rbase < 32) {
#pragma unroll
                for (int r = 0; r < 4; ++r) {
                    const int row = rbase + r;
                    *reinterpret_cast<float2*>(&pbuf[kg][row][cg2 ^ (row & 12)])
                        = make_float2(acc[r][0], acc[r][1]);
                }
            }
            __syncthreads();
            if (tid < 512) {
                const int row = tid >> 4, col = tid & 15;
                float s = 0.f;
#pragma unroll
                for (int g = 0; g < 8; ++g) s += pbuf[g][row][col ^ (row & 12)];
                sout[(size_t)row * RSZ + c0 + col] = tanhf(s);
            }
            __syncthreads();
            if (rbase >= 32) {
#pragma unroll
                for (int r = 0; r < 4; ++r) {
                    const int row = rbase + r, rl = row & 31;
                    *reinterpret_cast<float2*>(&pbuf[kg][rl][cg2 ^ (rl & 12)])
                        = make_float2(acc[r][0], acc[r][1]);
                }
            }
            __syncthreads();
            if (tid < 512) {
                const int rl = tid >> 4, col = tid & 15;
                float s = 0.f;
#pragma unroll
                for (int g = 0; g < 8; ++g) s += pbuf[g][rl][col ^ (rl & 12)];
                sout[(size_t)(32 + rl) * RSZ + c0 + col] = tanhf(s);
            }
        }

        // ---- hierarchical device barrier (monotonic epoch) ----
        __syncthreads();
        if (tid == 0) {
            __threadfence();                 // release
            const unsigned target = (unsigned)(tick + 1);
            unsigned prev = atomicAdd(&leaf[(blk & 7) << 4], 1u);
            if (prev == 24u * target - 1u) { // last of this leaf
                prev = atomicAdd(root, 1u);
                if (prev == 8u * target - 1u)
                    __hip_atomic_store(epoch, target, __ATOMIC_RELEASE,
                                       __HIP_MEMORY_SCOPE_AGENT);
            }
            while (__hip_atomic_load(epoch, __ATOMIC_RELAXED,
                                     __HIP_MEMORY_SCOPE_AGENT) < target)
                __builtin_amdgcn_s_sleep(1);
            __threadfence();                 // acquire
        }
        __syncthreads();
    }

    // ---- LayerNorm over h = s_2(T-1) (slot 1), blocks 0..63 ----
    if (blk < BB) {
        const float* h = states + ((size_t)2 * 2 + 1) * SLAB + (size_t)blk * RSZ;
        float* red = &pbuf[0][0][0];

        const float hv = h[tid];             // RSZ == NTHR
        float v = hv;
#pragma unroll
        for (int o = 32; o > 0; o >>= 1) v += __shfl_down(v, o, 64);
        if ((tid & 63) == 0) red[tid >> 6] = v;
        __syncthreads();
        if (tid == 0) {
            float s = 0.f;
#pragma unroll
            for (int i = 0; i < 16; ++i) s += red[i];
            red[20] = s / (float)RSZ;
        }
        __syncthreads();
        const float mu = red[20];
        const float d = hv - mu;
        v = d * d;
#pragma unroll
        for (int o = 32; o > 0; o >>= 1) v += __shfl_down(v, o, 64);
        __syncthreads();
        if ((tid & 63) == 0) red[tid >> 6] = v;
        __syncthreads();
        if (tid == 0) {
            float s = 0.f;
#pragma unroll
            for (int i = 0; i < 16; ++i) s += red[i];
            red[21] = rsqrtf(s / (float)RSZ + EPSLN);
        }
        __syncthreads();
        const float inv = red[21];
        out[blk * RSZ + tid] = d * inv * ln_w[tid] + ln_b[tid];
    }
}

extern "C" void kernel_launch(void* const* d_in, const int* in_sizes, int n_in,
                              void* d_out, int out_size, void* d_ws, size_t ws_size,
                              hipStream_t stream) {
    const int*   x       = (const int*)  d_in[0];
    const float* embed_w = (const float*)d_in[1];
    const float* Win0    = (const float*)d_in[2];
    const float* Win1    = (const float*)d_in[3];
    const float* Win2    = (const float*)d_in[4];
    const float* Rm0     = (const float*)d_in[5];
    const float* Rm1     = (const float*)d_in[6];
    const float* Rm2     = (const float*)d_in[7];
    const float* ln_w    = (const float*)d_in[8];
    const float* ln_b    = (const float*)d_in[9];
    float*       out     = (float*)d_out;
    float*       states  = (float*)d_ws;
    unsigned*    bar     = (unsigned*)((float*)d_ws + BAR_OFF);

    hipMemsetAsync(d_ws, 0, (size_t)BAR_OFF * sizeof(float) + 4096, stream);

    void* args[] = {
        (void*)&x, (void*)&embed_w,
        (void*)&Win0, (void*)&Win1, (void*)&Win2,
        (void*)&Rm0, (void*)&Rm1, (void*)&Rm2,
        (void*)&ln_w, (void*)&ln_b,
        (void*)&states, (void*)&bar, (void*)&out
    };
    hipLaunchCooperativeKernel(reinterpret_cast<void*>(reservoir_main),
                               dim3(NBLK), dim3(NTHR), args, 0, stream);
}

// Round 6
// 63017.847 us; speedup vs baseline: 1.5191x; 1.5191x over previous
//
#include <hip/hip_runtime.h>

#define VV    32000
#define EE    256
#define RSZ   1024
#define BB    64
#define TT    2048
#define NGRP  3
#define EPSLN 1e-5f

#define NBLK_PER_GRP 64
#define NBLK  (NBLK_PER_GRP * NGRP)   // 192 blocks
#define NTHR  1024                    // 16 waves = 8 k-groups x 128 threads
#define SLAB  (BB * RSZ)

#define BAR_OFF (NGRP * 2 * SLAB)     // floats offset of barrier words in d_ws

// one k-step (4 k-values): 2 rows x 4 cols FMAs against LDS weights
__device__ __forceinline__ void fma_step2x4(const float4 (&b)[2], const float* wrow,
                                            float (&acc)[2][4]) {
#pragma unroll
    for (int j = 0; j < 4; ++j) {
        const float4 w = *reinterpret_cast<const float4*>(wrow + j * 16);
#pragma unroll
        for (int r = 0; r < 2; ++r) {
            const float a = reinterpret_cast<const float*>(&b[r])[j];
            acc[r][0] = fmaf(a, w.x, acc[r][0]);
            acc[r][1] = fmaf(a, w.y, acc[r][1]);
            acc[r][2] = fmaf(a, w.z, acc[r][2]);
            acc[r][3] = fmaf(a, w.w, acc[r][3]);
        }
    }
}

// NSTEPS k-steps, depth-8 statically-indexed ring (2 float4/step = 64 ring regs)
template<int NSTEPS>
__device__ __forceinline__ void dot_stream(const float* p0, const float* p1,
                                           const float* w, float (&acc)[2][4]) {
    float4 ring[8][2];
    constexpr int PRO = (NSTEPS < 8) ? NSTEPS : 8;
#pragma unroll
    for (int s = 0; s < PRO; ++s) {
        ring[s][0] = *reinterpret_cast<const float4*>(p0 + s * 4);
        ring[s][1] = *reinterpret_cast<const float4*>(p1 + s * 4);
    }
    constexpr int MAIN = NSTEPS - PRO;
#pragma unroll
    for (int j = 0; j < MAIN; ++j) {          // static j -> ring[j&7] in regs
        fma_step2x4(ring[j & 7], w + j * 64, acc);
        ring[j & 7][0] = *reinterpret_cast<const float4*>(p0 + (j + 8) * 4);
        ring[j & 7][1] = *reinterpret_cast<const float4*>(p1 + (j + 8) * 4);
    }
#pragma unroll
    for (int j = MAIN; j < NSTEPS; ++j)       // drain ring
        fma_step2x4(ring[j & 7], w + j * 64, acc);
}

__global__ __launch_bounds__(NTHR)
void reservoir_main(const int*   __restrict__ x,        // [B,T]
                    const float* __restrict__ embed_w,  // [V,E]
                    const float* __restrict__ Win0,
                    const float* __restrict__ Win1,
                    const float* __restrict__ Win2,
                    const float* __restrict__ Rm0,
                    const float* __restrict__ Rm1,
                    const float* __restrict__ Rm2,
                    const float* __restrict__ ln_w,
                    const float* __restrict__ ln_b,
                    float*       __restrict__ states,
                    unsigned*    __restrict__ bar,
                    float*       __restrict__ out)
{
    const int blk   = blockIdx.x;
    const int grp   = blk >> 6;              // layer
    const int gb    = blk & 63;
    const int c0    = gb << 4;               // 16-col slice
    const int tid   = threadIdx.x;
    const int kg    = tid >> 7;              // 0..7
    const int idx   = tid & 127;
    const int rbase = (idx >> 2) << 1;       // 2 rows per lane: 0,2,...,62
    const int cg4   = (idx & 3) << 2;        // col quad: 0,4,8,12

    const float* Wl  = (grp == 0) ? Win0 : ((grp == 1) ? Win1 : Win2);
    const float* Rl  = (grp == 0) ? Rm0  : ((grp == 1) ? Rm1  : Rm2);
    const int    Kw  = (grp == 0) ? EE : RSZ;
    const int    Kw8 = Kw >> 3;              // 32 or 128 floats per kg

    __shared__ float wlds[2048 * 16];        // 128 KB weight slab
    __shared__ float pbuf[8][32][20];        // 20 KB partials (padded+swizzled)

    for (int i = tid; i < RSZ * 16; i += NTHR) {
        const int k = i >> 4, c = i & 15;
        wlds[i] = Rl[(size_t)k * RSZ + c0 + c];
    }
    for (int i = tid; i < Kw * 16; i += NTHR) {
        const int k = i >> 4, c = i & 15;
        wlds[RSZ * 16 + i] = Wl[(size_t)k * RSZ + c0 + c];
    }
    __syncthreads();

    // hierarchical barrier storage: 8 leaf lines + root + epoch
    unsigned* leaf  = bar;                   // leaf i at bar[i*16]
    unsigned* root  = bar + 128;
    unsigned* epoch = bar + 160;

    float* const sl = states + (size_t)grp * 2 * SLAB;
    const float* const wRb = wlds + (kg << 7) * 16 + cg4;
    const float* const wWb = wlds + (RSZ + kg * Kw8) * 16 + cg4;

    int xidx[2];
    if (grp == 0) {
#pragma unroll
        for (int r = 0; r < 2; ++r) xidx[r] = x[(rbase + r) * TT + 0];
    }

    for (int tick = 0; tick < TT + NGRP - 1; ++tick) {
        const int t = tick - grp;            // uniform per block
        if (0 <= t && t < TT) {
            const float* sprev = sl + (size_t)((t + 1) & 1) * SLAB;

            float acc[2][4] = {{0.f,0.f,0.f,0.f},{0.f,0.f,0.f,0.f}};

            {   // recurrent part: s_prev @ R_l (32 k-steps)
                const float* a0 = sprev + (size_t)(rbase + 0) * RSZ + (kg << 7);
                const float* a1 = sprev + (size_t)(rbase + 1) * RSZ + (kg << 7);
                dot_stream<32>(a0, a1, wRb, acc);
            }
            {   // input part: cur @ W_l
                if (grp == 0) {
                    const float* a0 = embed_w + (size_t)xidx[0] * EE + kg * Kw8;
                    const float* a1 = embed_w + (size_t)xidx[1] * EE + kg * Kw8;
                    dot_stream<8>(a0, a1, wWb, acc);
                } else {
                    const float* cb = states + ((size_t)(grp - 1) * 2 + (t & 1)) * SLAB;
                    const float* a0 = cb + (size_t)(rbase + 0) * RSZ + kg * Kw8;
                    const float* a1 = cb + (size_t)(rbase + 1) * RSZ + kg * Kw8;
                    dot_stream<32>(a0, a1, wWb, acc);
                }
            }

            // prefetch next tick's token indices (layer 0 only)
            if (grp == 0 && t + 1 < TT) {
#pragma unroll
                for (int r = 0; r < 2; ++r) xidx[r] = x[(rbase + r) * TT + t + 1];
            }

            // ---- flat reduce over 8 k-groups, two row-halves ----
            float* sout = sl + (size_t)(t & 1) * SLAB;

            if (idx < 64) {                  // rows 0..31
#pragma unroll
                for (int r = 0; r < 2; ++r) {
                    const int row = rbase + r;
                    *reinterpret_cast<float4*>(&pbuf[kg][row][cg4 ^ ((row & 3) << 2)])
                        = make_float4(acc[r][0], acc[r][1], acc[r][2], acc[r][3]);
                }
            }
            __syncthreads();
            if (tid < 512) {
                const int row = tid >> 4, col = tid & 15;
                const int cw  = ((col & 12) ^ ((row & 3) << 2)) | (col & 3);
                float s = 0.f;
#pragma unroll
                for (int g = 0; g < 8; ++g) s += pbuf[g][row][cw];
                sout[(size_t)row * RSZ + c0 + col] = tanhf(s);
            }
            __syncthreads();
            if (idx >= 64) {                 // rows 32..63
#pragma unroll
                for (int r = 0; r < 2; ++r) {
                    const int row = rbase + r, rl = row & 31;
                    *reinterpret_cast<float4*>(&pbuf[kg][rl][cg4 ^ ((rl & 3) << 2)])
                        = make_float4(acc[r][0], acc[r][1], acc[r][2], acc[r][3]);
                }
            }
            __syncthreads();
            if (tid < 512) {
                const int rl = tid >> 4, col = tid & 15;
                const int cw = ((col & 12) ^ ((rl & 3) << 2)) | (col & 3);
                float s = 0.f;
#pragma unroll
                for (int g = 0; g < 8; ++g) s += pbuf[g][rl][cw];
                sout[(size_t)(32 + rl) * RSZ + c0 + col] = tanhf(s);
            }
        }

        // ---- hierarchical device barrier (monotonic epoch) ----
        __syncthreads();
        if (tid == 0) {
            __threadfence();                 // release
            const unsigned target = (unsigned)(tick + 1);
            unsigned prev = atomicAdd(&leaf[(blk & 7) << 4], 1u);
            if (prev == 24u * target - 1u) { // last of this leaf
                prev = atomicAdd(root, 1u);
                if (prev == 8u * target - 1u)
                    __hip_atomic_store(epoch, target, __ATOMIC_RELEASE,
                                       __HIP_MEMORY_SCOPE_AGENT);
            }
            while (__hip_atomic_load(epoch, __ATOMIC_RELAXED,
                                     __HIP_MEMORY_SCOPE_AGENT) < target)
                __builtin_amdgcn_s_sleep(2);
            __threadfence();                 // acquire
        }
        __syncthreads();
    }

    // ---- LayerNorm over h = s_2(T-1) (slot 1), blocks 0..63 ----
    if (blk < BB) {
        const float* h = states + ((size_t)2 * 2 + 1) * SLAB + (size_t)blk * RSZ;
        float* red = &pbuf[0][0][0];

        const float hv = h[tid];             // RSZ == NTHR
        float v = hv;
#pragma unroll
        for (int o = 32; o > 0; o >>= 1) v += __shfl_down(v, o, 64);
        if ((tid & 63) == 0) red[tid >> 6] = v;
        __syncthreads();
        if (tid == 0) {
            float s = 0.f;
#pragma unroll
            for (int i = 0; i < 16; ++i) s += red[i];
            red[20] = s / (float)RSZ;
        }
        __syncthreads();
        const float mu = red[20];
        const float d = hv - mu;
        v = d * d;
#pragma unroll
        for (int o = 32; o > 0; o >>= 1) v += __shfl_down(v, o, 64);
        __syncthreads();
        if ((tid & 63) == 0) red[tid >> 6] = v;
        __syncthreads();
        if (tid == 0) {
            float s = 0.f;
#pragma unroll
            for (int i = 0; i < 16; ++i) s += red[i];
            red[21] = rsqrtf(s / (float)RSZ + EPSLN);
        }
        __syncthreads();
        const float inv = red[21];
        out[blk * RSZ + tid] = d * inv * ln_w[tid] + ln_b[tid];
    }
}

extern "C" void kernel_launch(void* const* d_in, const int* in_sizes, int n_in,
                              void* d_out, int out_size, void* d_ws, size_t ws_size,
                              hipStream_t stream) {
    const int*   x       = (const int*)  d_in[0];
    const float* embed_w = (const float*)d_in[1];
    const float* Win0    = (const float*)d_in[2];
    const float* Win1    = (const float*)d_in[3];
    const float* Win2    = (const float*)d_in[4];
    const float* Rm0     = (const float*)d_in[5];
    const float* Rm1     = (const float*)d_in[6];
    const float* Rm2     = (const float*)d_in[7];
    const float* ln_w    = (const float*)d_in[8];
    const float* ln_b    = (const float*)d_in[9];
    float*       out     = (float*)d_out;
    float*       states  = (float*)d_ws;
    unsigned*    bar     = (unsigned*)((float*)d_ws + BAR_OFF);

    hipMemsetAsync(d_ws, 0, (size_t)BAR_OFF * sizeof(float) + 4096, stream);

    void* args[] = {
        (void*)&x, (void*)&embed_w,
        (void*)&Win0, (void*)&Win1, (void*)&Win2,
        (void*)&Rm0, (void*)&Rm1, (void*)&Rm2,
        (void*)&ln_w, (void*)&ln_b,
        (void*)&states, (void*)&bar, (void*)&out
    };
    hipLaunchCooperativeKernel(reinterpret_cast<void*>(reservoir_main),
                               dim3(NBLK), dim3(NTHR), args, 0, stream);
}

// Round 7
// 61326.074 us; speedup vs baseline: 1.5610x; 1.0276x over previous
//
#include <hip/hip_runtime.h>

#define VV    32000
#define EE    256
#define RSZ   1024
#define BB    64
#define TT    2048
#define NGRP  3
#define EPSLN 1e-5f

#define NBLK_PER_GRP 64
#define NBLK  (NBLK_PER_GRP * NGRP)   // 192 blocks
#define NTHR  512                     // 8 waves = 8 k-groups x 64 threads
#define SLAB  (BB * RSZ)

#define BAR_OFF (NGRP * 2 * SLAB)     // floats offset of barrier words in d_ws

// one k-step (4 k-values): 4 rows x 4 cols FMAs against LDS weights
__device__ __forceinline__ void fma_step4x4(const float4 (&b)[4], const float* wrow,
                                            float (&acc)[4][4]) {
#pragma unroll
    for (int j = 0; j < 4; ++j) {
        const float4 w = *reinterpret_cast<const float4*>(wrow + j * 16);
#pragma unroll
        for (int r = 0; r < 4; ++r) {
            const float a = reinterpret_cast<const float*>(&b[r])[j];
            acc[r][0] = fmaf(a, w.x, acc[r][0]);
            acc[r][1] = fmaf(a, w.y, acc[r][1]);
            acc[r][2] = fmaf(a, w.z, acc[r][2]);
            acc[r][3] = fmaf(a, w.w, acc[r][3]);
        }
    }
}

// NSTEPS k-steps, depth-4 statically-indexed ring (4 float4/step = 64 ring regs)
template<int NSTEPS>
__device__ __forceinline__ void dot_stream(const float* const (&p)[4],
                                           const float* w, float (&acc)[4][4]) {
    float4 ring[4][4];
    constexpr int PRO = (NSTEPS < 4) ? NSTEPS : 4;
#pragma unroll
    for (int s = 0; s < PRO; ++s)
#pragma unroll
        for (int r = 0; r < 4; ++r)
            ring[s][r] = *reinterpret_cast<const float4*>(p[r] + s * 4);

    constexpr int MAIN = NSTEPS - PRO;
#pragma unroll
    for (int j = 0; j < MAIN; ++j) {          // static j -> ring[j&3] in regs
        fma_step4x4(ring[j & 3], w + j * 64, acc);
#pragma unroll
        for (int r = 0; r < 4; ++r)
            ring[j & 3][r] = *reinterpret_cast<const float4*>(p[r] + (j + 4) * 4);
    }
#pragma unroll
    for (int j = MAIN; j < NSTEPS; ++j)       // drain ring
        fma_step4x4(ring[j & 3], w + j * 64, acc);
}

__global__ __launch_bounds__(NTHR, 2)
void reservoir_main(const int*   __restrict__ x,        // [B,T]
                    const float* __restrict__ embed_w,  // [V,E]
                    const float* __restrict__ Win0,
                    const float* __restrict__ Win1,
                    const float* __restrict__ Win2,
                    const float* __restrict__ Rm0,
                    const float* __restrict__ Rm1,
                    const float* __restrict__ Rm2,
                    const float* __restrict__ ln_w,
                    const float* __restrict__ ln_b,
                    float*       __restrict__ states,
                    unsigned*    __restrict__ bar,
                    float*       __restrict__ out)
{
    const int blk   = blockIdx.x;
    const int grp   = blk >> 6;              // layer
    const int gb    = blk & 63;
    const int c0    = gb << 4;               // 16-col slice
    const int tid   = threadIdx.x;
    const int kg    = tid >> 6;              // 0..7 (one wave each)
    const int idx   = tid & 63;
    const int rbase = (idx >> 2) << 2;       // 4 rows per lane: 0,4,...,60
    const int cg4   = (idx & 3) << 2;        // col quad: 0,4,8,12

    const float* Wl  = (grp == 0) ? Win0 : ((grp == 1) ? Win1 : Win2);
    const float* Rl  = (grp == 0) ? Rm0  : ((grp == 1) ? Rm1  : Rm2);
    const int    Kw  = (grp == 0) ? EE : RSZ;
    const int    Kw8 = Kw >> 3;              // 32 or 128 floats per kg

    __shared__ float wlds[2048 * 16];        // 128 KB weight slab
    __shared__ float pbuf[8][32][20];        // 20 KB partials (padded+swizzled)

    for (int i = tid; i < RSZ * 16; i += NTHR) {
        const int k = i >> 4, c = i & 15;
        wlds[i] = Rl[(size_t)k * RSZ + c0 + c];
    }
    for (int i = tid; i < Kw * 16; i += NTHR) {
        const int k = i >> 4, c = i & 15;
        wlds[RSZ * 16 + i] = Wl[(size_t)k * RSZ + c0 + c];
    }
    __syncthreads();

    // hierarchical barrier storage: 8 leaf lines + root + epoch
    unsigned* leaf  = bar;                   // leaf i at bar[i*16]
    unsigned* root  = bar + 128;
    unsigned* epoch = bar + 160;

    float* const sl = states + (size_t)grp * 2 * SLAB;
    const float* const wRb = wlds + (kg << 7) * 16 + cg4;
    const float* const wWb = wlds + (RSZ + kg * Kw8) * 16 + cg4;

    int xidx[4];
    if (grp == 0) {
#pragma unroll
        for (int r = 0; r < 4; ++r) xidx[r] = x[(rbase + r) * TT + 0];
    }

    for (int tick = 0; tick < TT + NGRP - 1; ++tick) {
        const int t = tick - grp;            // uniform per block
        if (0 <= t && t < TT) {
            const float* sprev = sl + (size_t)((t + 1) & 1) * SLAB;

            float acc[4][4];
#pragma unroll
            for (int r = 0; r < 4; ++r)
#pragma unroll
                for (int c = 0; c < 4; ++c) acc[r][c] = 0.f;

            {   // recurrent part: s_prev @ R_l (32 k-steps)
                const float* aR[4];
#pragma unroll
                for (int r = 0; r < 4; ++r)
                    aR[r] = sprev + (size_t)(rbase + r) * RSZ + (kg << 7);
                dot_stream<32>(aR, wRb, acc);
            }
            {   // input part: cur @ W_l
                const float* aW[4];
                if (grp == 0) {
#pragma unroll
                    for (int r = 0; r < 4; ++r)
                        aW[r] = embed_w + (size_t)xidx[r] * EE + kg * Kw8;
                    dot_stream<8>(aW, wWb, acc);
                } else {
                    const float* cb = states + ((size_t)(grp - 1) * 2 + (t & 1)) * SLAB;
#pragma unroll
                    for (int r = 0; r < 4; ++r)
                        aW[r] = cb + (size_t)(rbase + r) * RSZ + kg * Kw8;
                    dot_stream<32>(aW, wWb, acc);
                }
            }

            // prefetch next tick's token indices (layer 0 only)
            if (grp == 0 && t + 1 < TT) {
#pragma unroll
                for (int r = 0; r < 4; ++r) xidx[r] = x[(rbase + r) * TT + t + 1];
            }

            // ---- flat reduce over 8 k-groups, two row-halves ----
            float* sout = sl + (size_t)(t & 1) * SLAB;

            if (idx < 32) {                  // rows 0..31
#pragma unroll
                for (int r = 0; r < 4; ++r) {
                    const int row = rbase + r;
                    *reinterpret_cast<float4*>(&pbuf[kg][row][cg4 ^ ((row & 3) << 2)])
                        = make_float4(acc[r][0], acc[r][1], acc[r][2], acc[r][3]);
                }
            }
            __syncthreads();
            {
                const int row = tid >> 4, col = tid & 15;    // 512 thr = 32x16
                const int cw  = ((col & 12) ^ ((row & 3) << 2)) | (col & 3);
                float s = 0.f;
#pragma unroll
                for (int g = 0; g < 8; ++g) s += pbuf[g][row][cw];
                sout[(size_t)row * RSZ + c0 + col] = tanhf(s);
            }
            __syncthreads();
            if (idx >= 32) {                 // rows 32..63
#pragma unroll
                for (int r = 0; r < 4; ++r) {
                    const int row = rbase + r, rl = row & 31;
                    *reinterpret_cast<float4*>(&pbuf[kg][rl][cg4 ^ ((rl & 3) << 2)])
                        = make_float4(acc[r][0], acc[r][1], acc[r][2], acc[r][3]);
                }
            }
            __syncthreads();
            {
                const int rl = tid >> 4, col = tid & 15;
                const int cw = ((col & 12) ^ ((rl & 3) << 2)) | (col & 3);
                float s = 0.f;
#pragma unroll
                for (int g = 0; g < 8; ++g) s += pbuf[g][rl][cw];
                sout[(size_t)(32 + rl) * RSZ + c0 + col] = tanhf(s);
            }
        }

        // ---- hierarchical device barrier (monotonic epoch) ----
        __syncthreads();
        if (tid == 0) {
            __threadfence();                 // release
            const unsigned target = (unsigned)(tick + 1);
            unsigned prev = atomicAdd(&leaf[(blk & 7) << 4], 1u);
            if (prev == 24u * target - 1u) { // last of this leaf
                prev = atomicAdd(root, 1u);
                if (prev == 8u * target - 1u)
                    __hip_atomic_store(epoch, target, __ATOMIC_RELEASE,
                                       __HIP_MEMORY_SCOPE_AGENT);
            }
            while (__hip_atomic_load(epoch, __ATOMIC_RELAXED,
                                     __HIP_MEMORY_SCOPE_AGENT) < target)
                __builtin_amdgcn_s_sleep(2);
            __threadfence();                 // acquire
        }
        __syncthreads();
    }

    // ---- LayerNorm over h = s_2(T-1) (slot 1), blocks 0..63, 2 elems/thread ----
    if (blk < BB) {
        const float* h = states + ((size_t)2 * 2 + 1) * SLAB + (size_t)blk * RSZ;
        float* red = &pbuf[0][0][0];

        const float hv0 = h[tid];
        const float hv1 = h[tid + 512];
        float v = hv0 + hv1;
#pragma unroll
        for (int o = 32; o > 0; o >>= 1) v += __shfl_down(v, o, 64);
        if ((tid & 63) == 0) red[tid >> 6] = v;
        __syncthreads();
        if (tid == 0) {
            float s = 0.f;
#pragma unroll
            for (int i = 0; i < 8; ++i) s += red[i];
            red[20] = s / (float)RSZ;
        }
        __syncthreads();
        const float mu = red[20];
        const float d0 = hv0 - mu, d1 = hv1 - mu;
        v = d0 * d0 + d1 * d1;
#pragma unroll
        for (int o = 32; o > 0; o >>= 1) v += __shfl_down(v, o, 64);
        __syncthreads();
        if ((tid & 63) == 0) red[tid >> 6] = v;
        __syncthreads();
        if (tid == 0) {
            float s = 0.f;
#pragma unroll
            for (int i = 0; i < 8; ++i) s += red[i];
            red[21] = rsqrtf(s / (float)RSZ + EPSLN);
        }
        __syncthreads();
        const float inv = red[21];
        out[blk * RSZ + tid]       = d0 * inv * ln_w[tid]       + ln_b[tid];
        out[blk * RSZ + tid + 512] = d1 * inv * ln_w[tid + 512] + ln_b[tid + 512];
    }
}

extern "C" void kernel_launch(void* const* d_in, const int* in_sizes, int n_in,
                              void* d_out, int out_size, void* d_ws, size_t ws_size,
                              hipStream_t stream) {
    const int*   x       = (const int*)  d_in[0];
    const float* embed_w = (const float*)d_in[1];
    const float* Win0    = (const float*)d_in[2];
    const float* Win1    = (const float*)d_in[3];
    const float* Win2    = (const float*)d_in[4];
    const float* Rm0     = (const float*)d_in[5];
    const float* Rm1     = (const float*)d_in[6];
    const float* Rm2     = (const float*)d_in[7];
    const float* ln_w    = (const float*)d_in[8];
    const float* ln_b    = (const float*)d_in[9];
    float*       out     = (float*)d_out;
    float*       states  = (float*)d_ws;
    unsigned*    bar     = (unsigned*)((float*)d_ws + BAR_OFF);

    hipMemsetAsync(d_ws, 0, (size_t)BAR_OFF * sizeof(float) + 4096, stream);

    void* args[] = {
        (void*)&x, (void*)&embed_w,
        (void*)&Win0, (void*)&Win1, (void*)&Win2,
        (void*)&Rm0, (void*)&Rm1, (void*)&Rm2,
        (void*)&ln_w, (void*)&ln_b,
        (void*)&states, (void*)&bar, (void*)&out
    };
    hipLaunchCooperativeKernel(reinterpret_cast<void*>(reservoir_main),
                               dim3(NBLK), dim3(NTHR), args, 0, stream);
}